// Round 6
// baseline (80.305 us; speedup 1.0000x reference)
//
#include <hip/hip_runtime.h>

// ============================================================================
// INSTRUMENTED MEASUREMENT BUILD (R6): kernels identical to R5 but each body
// repeats REP times (idempotent -> same output, deterministic). This pushes
// each dispatch above the profiler's top-5 cutoff so we get per-kernel
// dur_us / VALUBusy / FETCH. Divide profiled dur by REP for true kernel time.
// ============================================================================
#define REP 10

#define BSZ 4
#define CH  64
#define CE  8      // C/8
#define HW  4096
#define PJ  1088   // per-block partials: A 512 + B 512 + S 64

__global__ __launch_bounds__(512) void k1_kernel(
    const float* __restrict__ x,
    const float* __restrict__ qlw, const float* __restrict__ qlb,
    const float* __restrict__ kw,  const float* __restrict__ kb,
    const float* __restrict__ vw,  const float* __restrict__ vb,
    const float* __restrict__ qgw, const float* __restrict__ qgb,
    float* __restrict__ kbuf, float* __restrict__ qlbuf, float* __restrict__ Pbuf)
{
    __shared__ float vT[CH][68];
    __shared__ float kT[CE][64];

    const int tid  = threadIdx.x;
    const int lane = tid & 63;
    const int g    = __builtin_amdgcn_readfirstlane(tid >> 6);  // wave 0..7
    const int b    = blockIdx.x >> 6;
    const int p0   = (blockIdx.x & 63) << 6;
    const int p    = p0 | lane;

    for (int rep = 0; rep < REP; ++rep) {
        float xv[CH];
#pragma unroll
        for (int c = 0; c < CH; ++c) xv[c] = x[(((b << 6) + c) << 12) + p];

        const int o0 = g * 10;           // scalar
#pragma unroll
        for (int i = 0; i < 10; ++i) {
            const int o = o0 + i;        // scalar 0..79
            const float* wr;
            float bias;
            if (o < 8)       { wr = kw  + (o << 6);        bias = kb[o]; }
            else if (o < 16) { wr = qlw + ((o - 8) << 6);  bias = qlb[o - 8]; }
            else             { wr = vw  + ((o - 16) << 6); bias = vb[o - 16]; }
            float acc = bias;
#pragma unroll
            for (int c = 0; c < CH; ++c) acc += wr[c] * xv[c];
            if (o < 8) {
                kbuf[(((b << 3) + o) << 12) + p] = acc;
                kT[o][lane] = acc;
            } else if (o < 16) {
                qlbuf[(((b << 3) + (o - 8)) << 12) + p] = acc;
            } else {
                vT[o - 16][lane] = acc;
            }
        }
        __syncthreads();

        {
            const int e = g;             // scalar
            float a = 0.f, bb = 0.f;
#pragma unroll
            for (int pp = 0; pp < 64; pp += 4) {
                const float4 vv = *reinterpret_cast<const float4*>(&vT[lane][pp]);
                const float4 kk = *reinterpret_cast<const float4*>(&kT[e][pp]);
                const float w0 = qgw[((p0 + pp + 0) << 3) + e];
                const float w1 = qgw[((p0 + pp + 1) << 3) + e];
                const float w2 = qgw[((p0 + pp + 2) << 3) + e];
                const float w3 = qgw[((p0 + pp + 3) << 3) + e];
                a  += vv.x * w0 + vv.y * w1 + vv.z * w2 + vv.w * w3;
                bb += vv.x * kk.x + vv.y * kk.y + vv.z * kk.z + vv.w * kk.w;
            }
            float* P = Pbuf + (size_t)blockIdx.x * PJ;
            P[(e << 6) + lane] = a;
            P[512 + (e << 6) + lane] = bb;
            if (g == 0) {
                float s = 0.f;
#pragma unroll
                for (int pp = 0; pp < 64; pp += 4) {
                    const float4 vv = *reinterpret_cast<const float4*>(&vT[lane][pp]);
                    s += vv.x * qgb[p0 + pp] + vv.y * qgb[p0 + pp + 1]
                       + vv.z * qgb[p0 + pp + 2] + vv.w * qgb[p0 + pp + 3];
                }
                P[1024 + lane] = s;
            }
        }
        __syncthreads();                 // WAR: LDS rewritten next rep
        asm volatile("" ::: "memory");   // forbid cross-rep CSE/DCE
    }
}

__global__ __launch_bounds__(512) void k2_kernel(
    const float* __restrict__ x,
    const float* __restrict__ kbuf, const float* __restrict__ qlbuf,
    const float* __restrict__ Pbuf,
    const float* __restrict__ ggp, const float* __restrict__ glp,
    float* __restrict__ out)
{
    __shared__ float sA[CH][8], sB[CH][8], sS[CH];
    const int tid  = threadIdx.x;
    const int lane = tid & 63;
    const int g    = __builtin_amdgcn_readfirstlane(tid >> 6);  // 0..7
    const int b    = blockIdx.x >> 6;
    const int p    = ((blockIdx.x & 63) << 6) | lane;

    for (int rep = 0; rep < REP; ++rep) {
        const float gg = ggp[0], gl = glp[0];

        const float* Pb = Pbuf + (size_t)(b << 6) * PJ;
        for (int j = tid; j < PJ; j += 512) {
            float acc = 0.f;
#pragma unroll 16
            for (int s2 = 0; s2 < 64; ++s2) acc += Pb[(size_t)s2 * PJ + j];
            if (j < 512)       sA[j & 63][j >> 6] = gg * acc;
            else if (j < 1024) sB[j & 63][(j - 512) >> 6] = gl * acc;
            else               sS[j - 1024] = gg * acc;
        }

        const float* kgp = kbuf + ((size_t)b << 15) + ((size_t)p << 3);
        const float4 kg0 = *reinterpret_cast<const float4*>(kgp);
        const float4 kg1 = *reinterpret_cast<const float4*>(kgp + 4);
        float ql[CE];
#pragma unroll
        for (int e = 0; e < CE; ++e) ql[e] = qlbuf[(((b << 3) + e) << 12) + p];

        __syncthreads();

        const int c0 = g << 3;   // scalar: 8 channels per wave
#pragma unroll
        for (int ci = 0; ci < 8; ++ci) {
            const int c = c0 + ci;   // scalar
            const float4 A0 = *reinterpret_cast<const float4*>(&sA[c][0]);
            const float4 A1 = *reinterpret_cast<const float4*>(&sA[c][4]);
            const float4 B0 = *reinterpret_cast<const float4*>(&sB[c][0]);
            const float4 B1 = *reinterpret_cast<const float4*>(&sB[c][4]);
            float r = sS[c];
            r += kg0.x * A0.x + kg0.y * A0.y + kg0.z * A0.z + kg0.w * A0.w;
            r += kg1.x * A1.x + kg1.y * A1.y + kg1.z * A1.z + kg1.w * A1.w;
            r += ql[0] * B0.x + ql[1] * B0.y + ql[2] * B0.z + ql[3] * B0.w;
            r += ql[4] * B1.x + ql[5] * B1.y + ql[6] * B1.z + ql[7] * B1.w;
            const int idx = (((b << 6) + c) << 12) + p;
            out[idx] = r + x[idx];
        }
        __syncthreads();                 // WAR: LDS rewritten next rep
        asm volatile("" ::: "memory");
    }
}

extern "C" void kernel_launch(void* const* d_in, const int* in_sizes, int n_in,
                              void* d_out, int out_size, void* d_ws, size_t ws_size,
                              hipStream_t stream) {
    const float* x   = (const float*)d_in[0];
    const float* qlw = (const float*)d_in[1];
    const float* qlb = (const float*)d_in[2];
    const float* kw  = (const float*)d_in[3];
    const float* kb  = (const float*)d_in[4];
    const float* vw  = (const float*)d_in[5];
    const float* vb  = (const float*)d_in[6];
    const float* qgw = (const float*)d_in[7];
    const float* qgb = (const float*)d_in[8];
    const float* gg  = (const float*)d_in[9];
    const float* gl  = (const float*)d_in[10];
    float* out = (float*)d_out;

    float* ws    = (float*)d_ws;
    float* kbuf  = ws;                        // 4*8*4096 = 131072 f
    float* qlbuf = kbuf + BSZ * CE * HW;      // 131072 f
    float* Pbuf  = qlbuf + BSZ * CE * HW;     // 256*1088 = 278528 f

    k1_kernel<<<256, 512, 0, stream>>>(x, qlw, qlb, kw, kb, vw, vb, qgw, qgb,
                                       kbuf, qlbuf, Pbuf);
    k2_kernel<<<256, 512, 0, stream>>>(x, kbuf, qlbuf, Pbuf, gg, gl, out);
}

// Round 7
// 37.731 us; speedup vs baseline: 2.1284x; 2.1284x over previous
//
#include <hip/hip_runtime.h>

#define BSZ 4
#define CH  64
#define CE  8      // C/8
#define HW  4096
#define PJ  1088   // per-block partials: A 512 + B 512 + S 64

// ---------------------------------------------------------------------------
// K1: per block = (batch b, 64 columns p0..p0+63). 512 threads = 8 waves.
// Conv weights via scalar pipe; k/q_l -> global; v -> LDS; block-partial
// A/B/S -> own Pbuf slot. (Identical to R5's k1.)
// ---------------------------------------------------------------------------
__global__ __launch_bounds__(512) void k1_kernel(
    const float* __restrict__ x,
    const float* __restrict__ qlw, const float* __restrict__ qlb,
    const float* __restrict__ kw,  const float* __restrict__ kb,
    const float* __restrict__ vw,  const float* __restrict__ vb,
    const float* __restrict__ qgw, const float* __restrict__ qgb,
    float* __restrict__ kbuf, float* __restrict__ qlbuf, float* __restrict__ Pbuf)
{
    __shared__ float vT[CH][68];     // [channel][pp]
    __shared__ float kT[CE][64];     // [e][pp]

    const int tid  = threadIdx.x;
    const int lane = tid & 63;
    const int g    = __builtin_amdgcn_readfirstlane(tid >> 6);  // wave 0..7
    const int b    = blockIdx.x >> 6;
    const int p0   = (blockIdx.x & 63) << 6;
    const int p    = p0 | lane;

    float xv[CH];
#pragma unroll
    for (int c = 0; c < CH; ++c) xv[c] = x[(((b << 6) + c) << 12) + p];

    const int o0 = g * 10;           // scalar
#pragma unroll
    for (int i = 0; i < 10; ++i) {
        const int o = o0 + i;        // scalar 0..79
        const float* wr;
        float bias;
        if (o < 8)       { wr = kw  + (o << 6);        bias = kb[o]; }
        else if (o < 16) { wr = qlw + ((o - 8) << 6);  bias = qlb[o - 8]; }
        else             { wr = vw  + ((o - 16) << 6); bias = vb[o - 16]; }
        float acc = bias;
#pragma unroll
        for (int c = 0; c < CH; ++c) acc += wr[c] * xv[c];   // v_fmac v,s,v
        if (o < 8) {
            kbuf[(((b << 3) + o) << 12) + p] = acc;
            kT[o][lane] = acc;
        } else if (o < 16) {
            qlbuf[(((b << 3) + (o - 8)) << 12) + p] = acc;
        } else {
            vT[o - 16][lane] = acc;
        }
    }
    __syncthreads();

    {
        const int e = g & 7;         // scalar
        float a = 0.f, bb = 0.f;
#pragma unroll
        for (int pp = 0; pp < 64; pp += 4) {
            const float4 vv = *reinterpret_cast<const float4*>(&vT[lane][pp]);
            const float4 kk = *reinterpret_cast<const float4*>(&kT[e][pp]);
            const float w0 = qgw[((p0 + pp + 0) << 3) + e];   // s_load
            const float w1 = qgw[((p0 + pp + 1) << 3) + e];
            const float w2 = qgw[((p0 + pp + 2) << 3) + e];
            const float w3 = qgw[((p0 + pp + 3) << 3) + e];
            a  += vv.x * w0 + vv.y * w1 + vv.z * w2 + vv.w * w3;
            bb += vv.x * kk.x + vv.y * kk.y + vv.z * kk.z + vv.w * kk.w;
        }
        float* P = Pbuf + (size_t)blockIdx.x * PJ;
        P[(e << 6) + lane] = a;              // coalesced per wave
        P[512 + (e << 6) + lane] = bb;
        if (g == 0) {
            float s = 0.f;
#pragma unroll
            for (int pp = 0; pp < 64; pp += 4) {
                const float4 vv = *reinterpret_cast<const float4*>(&vT[lane][pp]);
                s += vv.x * qgb[p0 + pp] + vv.y * qgb[p0 + pp + 1]
                   + vv.z * qgb[p0 + pp + 2] + vv.w * qgb[p0 + pp + 3];
            }
            P[1024 + lane] = s;
        }
    }
}

// ---------------------------------------------------------------------------
// KR: reduce Pbuf's 64 slots per batch -> F[b][1088], gg/gl folded in.
// 17 blocks x 256 threads = 4352 threads, one output each; 64 independent
// strided loads per thread, coalesced across lanes. Pbuf read ONCE.
// ---------------------------------------------------------------------------
__global__ __launch_bounds__(256) void kr_kernel(
    const float* __restrict__ Pbuf,
    const float* __restrict__ ggp, const float* __restrict__ glp,
    float* __restrict__ Fbuf)
{
    const int t = blockIdx.x * 256 + threadIdx.x;   // 0..4351
    const int b = t / PJ;
    const int j = t - b * PJ;

    const float* Pb = Pbuf + (size_t)(b << 6) * PJ + j;
    float acc = 0.f;
#pragma unroll
    for (int s = 0; s < 64; ++s) acc += Pb[(size_t)s * PJ];

    const float scale = (j >= 512 && j < 1024) ? glp[0] : ggp[0];
    Fbuf[t] = scale * acc;
}

// ---------------------------------------------------------------------------
// K2: pure streaming combine, no LDS, no barriers.
//   out[b,c,p] = dot8(kg[p], F.A[c]) + F.S[c] + dot8(ql[p], F.B[c]) + x[b,c,p]
// F indices are wave-uniform -> s_load via constant cache (17 KB total).
// kg[b,p,e] = kbuf flat at b*32768 + p*8 + e (raw reshape regroup).
// ---------------------------------------------------------------------------
__global__ __launch_bounds__(512) void k2_kernel(
    const float* __restrict__ x,
    const float* __restrict__ kbuf, const float* __restrict__ qlbuf,
    const float* __restrict__ Fbuf,
    float* __restrict__ out)
{
    const int tid  = threadIdx.x;
    const int lane = tid & 63;
    const int g    = __builtin_amdgcn_readfirstlane(tid >> 6);  // 0..7
    const int b    = blockIdx.x >> 6;
    const int p    = ((blockIdx.x & 63) << 6) | lane;

    const float* Fb = Fbuf + b * PJ;     // wave-uniform base

    const float* kgp = kbuf + ((size_t)b << 15) + ((size_t)p << 3);
    const float4 kg0 = *reinterpret_cast<const float4*>(kgp);
    const float4 kg1 = *reinterpret_cast<const float4*>(kgp + 4);
    const float kg[8] = {kg0.x, kg0.y, kg0.z, kg0.w, kg1.x, kg1.y, kg1.z, kg1.w};
    float ql[CE];
#pragma unroll
    for (int e = 0; e < CE; ++e) ql[e] = qlbuf[(((b << 3) + e) << 12) + p];

    const int c0 = g << 3;   // scalar: 8 channels per wave
#pragma unroll
    for (int ci = 0; ci < 8; ++ci) {
        const int c = c0 + ci;   // scalar
        float r = Fb[1024 + c];                       // s_load
#pragma unroll
        for (int e = 0; e < CE; ++e) {
            r += kg[e] * Fb[(e << 6) + c];            // s_load operand
            r += ql[e] * Fb[512 + (e << 6) + c];      // s_load operand
        }
        const int idx = (((b << 6) + c) << 12) + p;
        out[idx] = r + x[idx];
    }
}

extern "C" void kernel_launch(void* const* d_in, const int* in_sizes, int n_in,
                              void* d_out, int out_size, void* d_ws, size_t ws_size,
                              hipStream_t stream) {
    const float* x   = (const float*)d_in[0];
    const float* qlw = (const float*)d_in[1];
    const float* qlb = (const float*)d_in[2];
    const float* kw  = (const float*)d_in[3];
    const float* kb  = (const float*)d_in[4];
    const float* vw  = (const float*)d_in[5];
    const float* vb  = (const float*)d_in[6];
    const float* qgw = (const float*)d_in[7];
    const float* qgb = (const float*)d_in[8];
    const float* gg  = (const float*)d_in[9];
    const float* gl  = (const float*)d_in[10];
    float* out = (float*)d_out;

    float* ws    = (float*)d_ws;
    float* kbuf  = ws;                        // 4*8*4096 = 131072 f
    float* qlbuf = kbuf + BSZ * CE * HW;      // 131072 f
    float* Pbuf  = qlbuf + BSZ * CE * HW;     // 256*1088 = 278528 f
    float* Fbuf  = Pbuf + 256 * PJ;           // 4*1088   = 4352 f

    k1_kernel<<<256, 512, 0, stream>>>(x, qlw, qlb, kw, kb, vw, vb, qgw, qgb,
                                       kbuf, qlbuf, Pbuf);
    kr_kernel<<<17, 256, 0, stream>>>(Pbuf, gg, gl, Fbuf);
    k2_kernel<<<256, 512, 0, stream>>>(x, kbuf, qlbuf, Fbuf, out);
}

// Round 8
// 35.523 us; speedup vs baseline: 2.2607x; 1.0622x over previous
//
#include <hip/hip_runtime.h>

#define BSZ 4
#define CH  64
#define CE  8      // C/8
#define HW  4096
#define PJ  1088   // per-block partials: A 512 + B 512 + S 64

// ---------------------------------------------------------------------------
// K1: per block = (batch b, 64 columns p0..p0+63). 512 threads = 8 waves.
// Conv weights via scalar pipe; k/q_l -> global; v -> LDS; block-partial
// A/B/S -> own Pbuf slot. (VERBATIM R5 k1 — known-good, ~2 us.)
// ---------------------------------------------------------------------------
__global__ __launch_bounds__(512) void k1_kernel(
    const float* __restrict__ x,
    const float* __restrict__ qlw, const float* __restrict__ qlb,
    const float* __restrict__ kw,  const float* __restrict__ kb,
    const float* __restrict__ vw,  const float* __restrict__ vb,
    const float* __restrict__ qgw, const float* __restrict__ qgb,
    float* __restrict__ kbuf, float* __restrict__ qlbuf, float* __restrict__ Pbuf)
{
    __shared__ float vT[CH][68];     // [channel][pp]
    __shared__ float kT[CE][64];     // [e][pp]

    const int tid  = threadIdx.x;
    const int lane = tid & 63;
    const int g    = __builtin_amdgcn_readfirstlane(tid >> 6);  // wave 0..7
    const int b    = blockIdx.x >> 6;
    const int p0   = (blockIdx.x & 63) << 6;
    const int p    = p0 | lane;

    float xv[CH];
#pragma unroll
    for (int c = 0; c < CH; ++c) xv[c] = x[(((b << 6) + c) << 12) + p];

    const int o0 = g * 10;           // scalar
#pragma unroll
    for (int i = 0; i < 10; ++i) {
        const int o = o0 + i;        // scalar 0..79
        const float* wr;
        float bias;
        if (o < 8)       { wr = kw  + (o << 6);        bias = kb[o]; }
        else if (o < 16) { wr = qlw + ((o - 8) << 6);  bias = qlb[o - 8]; }
        else             { wr = vw  + ((o - 16) << 6); bias = vb[o - 16]; }
        float acc = bias;
#pragma unroll
        for (int c = 0; c < CH; ++c) acc += wr[c] * xv[c];   // v_fmac v,s,v
        if (o < 8) {
            kbuf[(((b << 3) + o) << 12) + p] = acc;
            kT[o][lane] = acc;
        } else if (o < 16) {
            qlbuf[(((b << 3) + (o - 8)) << 12) + p] = acc;
        } else {
            vT[o - 16][lane] = acc;
        }
    }
    __syncthreads();

    {
        const int e = g & 7;         // scalar
        float a = 0.f, bb = 0.f;
#pragma unroll
        for (int pp = 0; pp < 64; pp += 4) {
            const float4 vv = *reinterpret_cast<const float4*>(&vT[lane][pp]);
            const float4 kk = *reinterpret_cast<const float4*>(&kT[e][pp]);
            const float w0 = qgw[((p0 + pp + 0) << 3) + e];   // s_load
            const float w1 = qgw[((p0 + pp + 1) << 3) + e];
            const float w2 = qgw[((p0 + pp + 2) << 3) + e];
            const float w3 = qgw[((p0 + pp + 3) << 3) + e];
            a  += vv.x * w0 + vv.y * w1 + vv.z * w2 + vv.w * w3;
            bb += vv.x * kk.x + vv.y * kk.y + vv.z * kk.z + vv.w * kk.w;
        }
        float* P = Pbuf + (size_t)blockIdx.x * PJ;
        P[(e << 6) + lane] = a;              // coalesced per wave
        P[512 + (e << 6) + lane] = bb;
        if (g == 0) {
            float s = 0.f;
#pragma unroll
            for (int pp = 0; pp < 64; pp += 4) {
                const float4 vv = *reinterpret_cast<const float4*>(&vT[lane][pp]);
                s += vv.x * qgb[p0 + pp] + vv.y * qgb[p0 + pp + 1]
                   + vv.z * qgb[p0 + pp + 2] + vv.w * qgb[p0 + pp + 3];
            }
            P[1024 + lane] = s;
        }
    }
}

// ---------------------------------------------------------------------------
// K2 (redesigned cold path):
//  - XCD-chunked swizzle: dispatch i -> logical L = (i&7)*32 + i>>3, so each
//    XCD hosts 32 same-batch blocks -> pulls ONE 278 KB Pbuf slice.
//  - prefetch kg/ql/x into registers FIRST (streams in flight under phase A).
//  - phase A: threads 0..271 own a j-quad; 64 independent float4 loads
//    (max MLP), scale by gg/gl, scatter to F[c][slot] in LDS.
//  - phase B: per-wave 8 channels; aligned b128 reads from F[c][24].
// ---------------------------------------------------------------------------
__global__ __launch_bounds__(512) void k2_kernel(
    const float* __restrict__ x,
    const float* __restrict__ kbuf, const float* __restrict__ qlbuf,
    const float* __restrict__ Pbuf,
    const float* __restrict__ ggp, const float* __restrict__ glp,
    float* __restrict__ out)
{
    __shared__ float F[CH][24];   // [c][slot]: 0-7 gg*A[e], 8-15 gl*B[e], 16 gg*S

    const int tid  = threadIdx.x;
    const int lane = tid & 63;
    const int g    = __builtin_amdgcn_readfirstlane(tid >> 6);  // 0..7
    const int L    = ((blockIdx.x & 7) << 5) | (blockIdx.x >> 3);
    const int b    = L >> 6;
    const int p    = ((L & 63) << 6) | lane;

    const float gg = ggp[0], gl = glp[0];

    // ---- prefetch phase-B operands (independent of Pbuf) ----
    const float* kgp = kbuf + ((size_t)b << 15) + ((size_t)p << 3);
    const float4 kg0 = *reinterpret_cast<const float4*>(kgp);
    const float4 kg1 = *reinterpret_cast<const float4*>(kgp + 4);
    float ql[CE];
#pragma unroll
    for (int e = 0; e < CE; ++e) ql[e] = qlbuf[(((b << 3) + e) << 12) + p];
    const int c0 = g << 3;        // scalar: this wave's 8 channels
    float xr[8];
#pragma unroll
    for (int ci = 0; ci < 8; ++ci) xr[ci] = x[(((b << 6) + c0 + ci) << 12) + p];

    // ---- phase A: reduce 64 slots; j-quad per thread, float4 MLP ----
    if (tid < 272) {
        const int j = tid << 2;   // 0,4,...,1084
        const float* Pq = Pbuf + (size_t)(b << 6) * PJ + j;
        float4 acc0 = {0.f, 0.f, 0.f, 0.f};
        float4 acc1 = {0.f, 0.f, 0.f, 0.f};
#pragma unroll
        for (int s = 0; s < 64; s += 2) {
            const float4 v0 = *reinterpret_cast<const float4*>(Pq + (size_t)s * PJ);
            const float4 v1 = *reinterpret_cast<const float4*>(Pq + (size_t)(s + 1) * PJ);
            acc0.x += v0.x; acc0.y += v0.y; acc0.z += v0.z; acc0.w += v0.w;
            acc1.x += v1.x; acc1.y += v1.y; acc1.z += v1.z; acc1.w += v1.w;
        }
        const float a0 = acc0.x + acc1.x;
        const float a1 = acc0.y + acc1.y;
        const float a2 = acc0.z + acc1.z;
        const float a3 = acc0.w + acc1.w;

        float scale; int c4, slot;
        if (j < 512)       { c4 = j & 63;              slot = j >> 6;          scale = gg; }
        else if (j < 1024) { const int jj = j - 512;   c4 = jj & 63;
                             slot = 8 + (jj >> 6);                             scale = gl; }
        else               { c4 = j - 1024;            slot = 16;              scale = gg; }
        F[c4 + 0][slot] = scale * a0;
        F[c4 + 1][slot] = scale * a1;
        F[c4 + 2][slot] = scale * a2;
        F[c4 + 3][slot] = scale * a3;
    }
    __syncthreads();

    // ---- phase B: 8 channels per wave, aligned b128 F reads ----
#pragma unroll
    for (int ci = 0; ci < 8; ++ci) {
        const int c = c0 + ci;    // scalar
        const float4 A0 = *reinterpret_cast<const float4*>(&F[c][0]);
        const float4 A1 = *reinterpret_cast<const float4*>(&F[c][4]);
        const float4 B0 = *reinterpret_cast<const float4*>(&F[c][8]);
        const float4 B1 = *reinterpret_cast<const float4*>(&F[c][12]);
        float r = F[c][16];
        r += kg0.x * A0.x + kg0.y * A0.y + kg0.z * A0.z + kg0.w * A0.w;
        r += kg1.x * A1.x + kg1.y * A1.y + kg1.z * A1.z + kg1.w * A1.w;
        r += ql[0] * B0.x + ql[1] * B0.y + ql[2] * B0.z + ql[3] * B0.w;
        r += ql[4] * B1.x + ql[5] * B1.y + ql[6] * B1.z + ql[7] * B1.w;
        const int idx = (((b << 6) + c) << 12) + p;
        out[idx] = r + xr[ci];
    }
}

extern "C" void kernel_launch(void* const* d_in, const int* in_sizes, int n_in,
                              void* d_out, int out_size, void* d_ws, size_t ws_size,
                              hipStream_t stream) {
    const float* x   = (const float*)d_in[0];
    const float* qlw = (const float*)d_in[1];
    const float* qlb = (const float*)d_in[2];
    const float* kw  = (const float*)d_in[3];
    const float* kb  = (const float*)d_in[4];
    const float* vw  = (const float*)d_in[5];
    const float* vb  = (const float*)d_in[6];
    const float* qgw = (const float*)d_in[7];
    const float* qgb = (const float*)d_in[8];
    const float* gg  = (const float*)d_in[9];
    const float* gl  = (const float*)d_in[10];
    float* out = (float*)d_out;

    float* ws    = (float*)d_ws;
    float* kbuf  = ws;                        // 4*8*4096 = 131072 f
    float* qlbuf = kbuf + BSZ * CE * HW;      // 131072 f
    float* Pbuf  = qlbuf + BSZ * CE * HW;     // 256*1088 = 278528 f

    k1_kernel<<<256, 512, 0, stream>>>(x, qlw, qlb, kw, kb, vw, vb, qgw, qgb,
                                       kbuf, qlbuf, Pbuf);
    k2_kernel<<<256, 512, 0, stream>>>(x, kbuf, qlbuf, Pbuf, gg, gl, out);
}